// Round 4
// baseline (928.079 us; speedup 1.0000x reference)
//
#include <hip/hip_runtime.h>
#include <hip/hip_bf16.h>
#include <cstdio>

// Problem constants (S6HistoryCompressor)
#define S_LEN 2048
#define BATCH 16
#define D_INP 1024
#define H_DIM 2048
#define SC    (S_LEN / 2)       // compressed length (step=2, rows 1,3,...,2047)
#define BH    (BATCH * H_DIM)   // 32768 independent recurrences
#define BH8   (BH / 8)          // 4096 vectorized lanes
#define NC    16                // scan chunks
#define CS    (S_LEN / NC)      // 128 steps per chunk

typedef __bf16 b16;
typedef __bf16 b16x8 __attribute__((ext_vector_type(8)));
typedef __bf16 b16x4 __attribute__((ext_vector_type(4)));
typedef float  f32x4 __attribute__((ext_vector_type(4)));

// XOR swizzle for LDS sub-tile [256 rows][32 bf16 cols], 16B granules.
// Physical slot p in row r holds LOGICAL granule p ^ ((r>>1)&3).
// Frag reads (lanes 0-15 = rows, l8 = granule) hit 2-way (free) aliasing only.
__device__ __forceinline__ int sw_off(int r, int k8) {
  return r * 32 + ((k8 ^ ((r >> 1) & 3)) << 3);
}

// Async global -> LDS, 16 B per lane. LDS dest = wave-uniform base + lane*16
// (hardware rule, m104/m108); swizzle is applied on the GLOBAL address side.
__device__ __forceinline__ void gl2lds16(const b16* g, b16* l) {
  __builtin_amdgcn_global_load_lds(
      (const __attribute__((address_space(1))) void*)g,
      (__attribute__((address_space(3))) void*)l, 16, 0, 0);
}

// Fast branchless softplus: log(1+e^t) = max(t,0) + log(1+e^-|t|).
__device__ __forceinline__ float softplus_fast(float t) {
  float e = __expf(-fabsf(t));
  return fmaxf(t, 0.f) + __logf(1.f + e);
}

// ---------------------------------------------------------------------------
// Conversions (vectorized: 16B/lane stores)
// ---------------------------------------------------------------------------
__global__ void cvt_x_kernel(const float* __restrict__ in, b16* __restrict__ out, int n8) {
  int i = blockIdx.x * 256 + threadIdx.x;
  if (i >= n8) return;
  float4 v0 = ((const float4*)in)[i * 2];
  float4 v1 = ((const float4*)in)[i * 2 + 1];
  b16x8 o = {(b16)v0.x, (b16)v0.y, (b16)v0.z, (b16)v0.w,
             (b16)v1.x, (b16)v1.y, (b16)v1.z, (b16)v1.w};
  ((b16x8*)out)[i] = o;
}

__global__ void prep_w_kernel(const float* __restrict__ Wd, const float* __restrict__ Win,
                              const float* __restrict__ WB, const float* __restrict__ Wc,
                              const float* __restrict__ Wcp,
                              b16* __restrict__ Wdu, b16* __restrict__ Wcb,
                              b16* __restrict__ Wcpb) {
  const int HD4 = (H_DIM * D_INP) / 4;
  int i = blockIdx.x * 256 + threadIdx.x;
  if (i >= HD4) return;
  float4 a = ((const float4*)Wd)[i];
  float4 b = ((const float4*)Win)[i];
  float4 c = ((const float4*)WB)[i];
  float4 d = ((const float4*)Wc)[i];
  float4 e = ((const float4*)Wcp)[i];
  ((b16x4*)Wdu)[i] = {(b16)a.x, (b16)a.y, (b16)a.z, (b16)a.w};
  ((b16x4*)Wdu)[HD4 + i] = {(b16)(b.x + c.x), (b16)(b.y + c.y), (b16)(b.z + c.z), (b16)(b.w + c.w)};
  ((b16x4*)Wcb)[i] = {(b16)d.x, (b16)d.y, (b16)d.z, (b16)d.w};
  ((b16x4*)Wcpb)[i] = {(b16)e.x, (b16)e.y, (b16)e.z, (b16)e.w};
}

// ---------------------------------------------------------------------------
// 8-phase 256x256 GEMM, m201-faithful: reads issued PRE-barrier so they drain
// during barrier-arrival skew and overlap other waves' MFMA clusters.
// C = A[M,K] x W[N,K]^T, bf16. 8 waves (512 thr), per-wave 128x64
// (acc[8][4]), BK=64. LDS: 2 x 64 KB buffers = Ah0|Ah1|Bh0|Bh1 sub-tiles.
//
// Phase = quadrant (ks-half x m-half), 16 MFMA each, NEW reads 8/4/8/4:
//   P0 (ks0,m-lo): read aLo(ks0)x4 + b(ks0)x4 | stage Ah0' | bar;lgkm0;MFMA;bar
//   P1 (ks0,m-hi): read aHi(ks0)x4            | stage Bh0' | vm(4);bar;...;bar
//   P2 (ks1,m-lo): read aLo(ks1)x4 + b(ks1)x4 | stage Ah1' | bar;...;bar
//   P3 (ks1,m-hi): read aHi(ks1)x4            | stage Bh1' | vm(4);bar;...;bar
// Gate chain (vmcnt pre-barrier -> barrier -> reads after that barrier makes
// the per-wave wait collective):
//   P1's vm(4) lands Ah1(t),Bh1(t)   -> read at P2/P3 (after bar1(P1))  OK
//   P3's vm(4) lands Ah0',Bh0'(t+1)  -> read at next P0 (after bar1(P3)) OK
// Buffer overwrite: stage into N+X at phase p issues after bar2(p-1); all
// reads of N's previous occupant completed before bar1 of the prior phase. OK
// ---------------------------------------------------------------------------
#define AH0 0
#define AH1 8192
#define BH0 16384
#define BH1 24576

template <int MODE>
__device__ __forceinline__ void stage_half(const b16* __restrict__ G, int ldg,
                                           int base_row, int kcol, b16* half_base,
                                           int wave, int lane, bool isA) {
#pragma unroll
  for (int q = 0; q < 2; ++q) {
    const int rbase = q * 128 + wave * 16;      // 16-row stripe (wave-uniform)
    const int r = rbase + (lane >> 2);          // row 0..255
    const int p = lane & 3;                     // physical granule
    const int gl = p ^ ((r >> 1) & 3);          // logical granule to fetch
    long grow = base_row + r;
    if (MODE == 1 && isA) grow = 2 * grow - (grow & 15) + 16;  // odd-t remap
    gl2lds16(G + grow * (long)ldg + kcol + gl * 8, half_base + rbase * 32);
  }
}

#define MFMA16(AF, BF, ROW0)                                                       \
  do {                                                                             \
    __builtin_amdgcn_s_setprio(1);                                                 \
    _Pragma("unroll") for (int i_ = 0; i_ < 4; i_++) {                             \
      _Pragma("unroll") for (int j_ = 0; j_ < 4; j_++) {                           \
        acc[ROW0 + i_][j_] = __builtin_amdgcn_mfma_f32_16x16x32_bf16(              \
            AF[i_], BF[j_], acc[ROW0 + i_][j_], 0, 0, 0);                          \
      }                                                                            \
    }                                                                              \
    __builtin_amdgcn_s_setprio(0);                                                 \
  } while (0)

template <int MODE>
__global__ __launch_bounds__(512, 2) void gemm8p(
    const b16* __restrict__ A, const b16* __restrict__ W, int K,
    const float* __restrict__ bias0, const float* __restrict__ bias1,
    const b16* __restrict__ hsel, b16* __restrict__ ob0, b16* __restrict__ ob1,
    float* __restrict__ of) {
  extern __shared__ b16 lds[];  // 2 x 32768 b16 = 128 KB
  const int tid  = threadIdx.x;
  const int lane = tid & 63;
  const int wave = tid >> 6;
  const int wm = wave >> 2, wn = wave & 3;
  const int lm = lane & 15;
  const int l8 = lane >> 4;

  // Bijective XCD swizzle (all grids have nwg % 8 == 0).
  const int gx  = gridDim.x;
  const int nwg = gx * gridDim.y;
  const int id0 = blockIdx.y * gx + blockIdx.x;
  const int sw  = (id0 & 7) * (nwg >> 3) + (id0 >> 3);
  const int m0 = (sw / gx) * 256;
  const int n0 = (sw % gx) * 256;

  f32x4 acc[8][4];
#pragma unroll
  for (int i = 0; i < 8; i++)
#pragma unroll
    for (int j = 0; j < 4; j++) acc[i][j] = (f32x4)0.f;

  const int NT = K >> 6;  // BK=64 tiles

  // Prologue: stage tile 0; collective-gate Ah0/Bh0 (vmcnt -> barrier).
  {
    stage_half<MODE>(A, K, m0, 0,  lds + AH0, wave, lane, true);
    stage_half<MODE>(W, K, n0, 0,  lds + BH0, wave, lane, false);
    stage_half<MODE>(A, K, m0, 32, lds + AH1, wave, lane, true);
    stage_half<MODE>(W, K, n0, 32, lds + BH1, wave, lane, false);
    asm volatile("s_waitcnt vmcnt(4)" ::: "memory");  // Ah0,Bh0 landed
    __builtin_amdgcn_s_barrier();
  }

  for (int t = 0; t < NT; ++t) {
    b16* const Cb = lds + ((t & 1) << 15);
    b16* const Nb = lds + (((t + 1) & 1) << 15);
    const int kn = (t + 1) << 6;
    const bool pf = (t + 1 < NT);
    b16x8 av[4], bv0[4], bv1[4];

    // ---- P0 (ks0, m-lo): reads pre-barrier; stage Ah0' ------------------
#pragma unroll
    for (int i = 0; i < 4; i++)
      av[i] = *(const b16x8*)(Cb + AH0 + sw_off(wm * 128 + i * 16 + lm, l8));
#pragma unroll
    for (int j = 0; j < 4; j++)
      bv0[j] = *(const b16x8*)(Cb + BH0 + sw_off(wn * 64 + j * 16 + lm, l8));
    if (pf) stage_half<MODE>(A, K, m0, kn, Nb + AH0, wave, lane, true);
    __builtin_amdgcn_s_barrier();
    asm volatile("s_waitcnt lgkmcnt(0)" ::: "memory");
    __builtin_amdgcn_sched_barrier(0);
    MFMA16(av, bv0, 0);
    __builtin_amdgcn_s_barrier();

    // ---- P1 (ks0, m-hi): reads pre-barrier; stage Bh0'; vm gates Ah1,Bh1(t)
#pragma unroll
    for (int i = 0; i < 4; i++)
      av[i] = *(const b16x8*)(Cb + AH0 + sw_off(wm * 128 + 64 + i * 16 + lm, l8));
    if (pf) {
      stage_half<MODE>(W, K, n0, kn, Nb + BH0, wave, lane, false);
      asm volatile("s_waitcnt vmcnt(4)" ::: "memory");
    } else {
      asm volatile("s_waitcnt vmcnt(0)" ::: "memory");
    }
    __builtin_amdgcn_s_barrier();
    asm volatile("s_waitcnt lgkmcnt(0)" ::: "memory");
    __builtin_amdgcn_sched_barrier(0);
    MFMA16(av, bv0, 4);
    __builtin_amdgcn_s_barrier();

    // ---- P2 (ks1, m-lo): reads pre-barrier; stage Ah1' ------------------
#pragma unroll
    for (int i = 0; i < 4; i++)
      av[i] = *(const b16x8*)(Cb + AH1 + sw_off(wm * 128 + i * 16 + lm, l8));
#pragma unroll
    for (int j = 0; j < 4; j++)
      bv1[j] = *(const b16x8*)(Cb + BH1 + sw_off(wn * 64 + j * 16 + lm, l8));
    if (pf) stage_half<MODE>(A, K, m0, kn + 32, Nb + AH1, wave, lane, true);
    __builtin_amdgcn_s_barrier();
    asm volatile("s_waitcnt lgkmcnt(0)" ::: "memory");
    __builtin_amdgcn_sched_barrier(0);
    MFMA16(av, bv1, 0);
    __builtin_amdgcn_s_barrier();

    // ---- P3 (ks1, m-hi): reads pre-barrier; stage Bh1'; vm gates Ah0',Bh0'
#pragma unroll
    for (int i = 0; i < 4; i++)
      av[i] = *(const b16x8*)(Cb + AH1 + sw_off(wm * 128 + 64 + i * 16 + lm, l8));
    if (pf) {
      stage_half<MODE>(W, K, n0, kn + 32, Nb + BH1, wave, lane, false);
      asm volatile("s_waitcnt vmcnt(4)" ::: "memory");
    }
    __builtin_amdgcn_s_barrier();
    asm volatile("s_waitcnt lgkmcnt(0)" ::: "memory");
    __builtin_amdgcn_sched_barrier(0);
    MFMA16(av, bv1, 4);
    __builtin_amdgcn_s_barrier();
  }

  // Epilogue. C/D layout: col = lane&15, row = (lane>>4)*4 + reg [m89/m91].
  if (MODE == 0) {
    const bool is_delta = (n0 < H_DIM);  // block-uniform (gx=16, 8+8 split)
    const float* bias = is_delta ? bias0 : bias1;
    b16* ob = is_delta ? ob0 : ob1;
    const int nc0 = (n0 & (H_DIM - 1)) + wn * 64 + lm;
    float bv[4];
#pragma unroll
    for (int j = 0; j < 4; j++) bv[j] = bias[nc0 + j * 16];
#pragma unroll
    for (int i = 0; i < 8; i++) {
      const long rb = m0 + wm * 128 + i * 16 + l8 * 4;
      b16* pr = ob + rb * H_DIM + nc0;
      if (is_delta) {
#pragma unroll
        for (int j = 0; j < 4; j++)
#pragma unroll
          for (int rg = 0; rg < 4; ++rg)
            pr[(long)rg * H_DIM + j * 16] = (b16)softplus_fast(acc[i][j][rg] + bv[j]);
      } else {
#pragma unroll
        for (int j = 0; j < 4; j++)
#pragma unroll
          for (int rg = 0; rg < 4; ++rg)
            pr[(long)rg * H_DIM + j * 16] = (b16)(acc[i][j][rg] + bv[j]);
      }
    }
  } else if (MODE == 1) {
    const int nc0 = n0 + wn * 64 + lm;
#pragma unroll
    for (int i = 0; i < 8; i++) {
      const long rb = m0 + wm * 128 + i * 16 + l8 * 4;
      const b16* hp = hsel + rb * H_DIM + nc0;
      b16* pr = ob0 + rb * H_DIM + nc0;
#pragma unroll
      for (int j = 0; j < 4; j++)
#pragma unroll
        for (int rg = 0; rg < 4; ++rg) {
          float hv = (float)hp[(long)rg * H_DIM + j * 16];
          pr[(long)rg * H_DIM + j * 16] = (b16)(acc[i][j][rg] * hv);
        }
    }
  } else {
    const int nc0 = n0 + wn * 64 + lm;
    float bv[4];
#pragma unroll
    for (int j = 0; j < 4; j++) bv[j] = bias0[nc0 + j * 16];
#pragma unroll
    for (int i = 0; i < 8; i++) {
      const long rb = m0 + wm * 128 + i * 16 + l8 * 4;
      float* pr = of + rb * D_INP + nc0;
#pragma unroll
      for (int j = 0; j < 4; j++)
#pragma unroll
        for (int rg = 0; rg < 4; ++rg)
          pr[(long)rg * D_INP + j * 16] = acc[i][j][rg] + bv[j];
    }
  }
}

// ---------------------------------------------------------------------------
// Fallback: 128x128 kernel (used only if 128 KB dynamic LDS opt-in refused).
// ---------------------------------------------------------------------------
template <int MODE>
__global__ __launch_bounds__(256, 2) void gemm_bt(
    const b16* __restrict__ A, const b16* __restrict__ W, int K,
    const float* __restrict__ bias0, const float* __restrict__ bias1,
    const b16* __restrict__ hsel, b16* __restrict__ ob0, b16* __restrict__ ob1,
    float* __restrict__ of) {
  __shared__ b16 As[128 * 32];
  __shared__ b16 Bs[128 * 32];
  const int tid  = threadIdx.x;
  const int lane = tid & 63;
  const int wave = tid >> 6;
  const int wr = wave >> 1, wc = wave & 1;
  const int m0 = blockIdx.y * 128;
  const int n0 = blockIdx.x * 128;
  const int lm = lane & 15;
  const int l8 = lane >> 4;
  const int rL  = wave * 16 + (lane >> 2);
  const int k8p = lane & 3;

  f32x4 acc[4][4];
#pragma unroll
  for (int i = 0; i < 4; i++)
#pragma unroll
    for (int j = 0; j < 4; j++) acc[i][j] = (f32x4)0.f;

  for (int k0 = 0; k0 < K; k0 += 32) {
#pragma unroll
    for (int hh = 0; hh < 2; ++hh) {
      const int r = rL + hh * 64;
      const int k8l = k8p ^ ((r >> 1) & 3);
      b16* ldsA = As + (wave * 16 + hh * 64) * 32;
      b16* ldsB = Bs + (wave * 16 + hh * 64) * 32;
      long arow = m0 + r;
      if (MODE == 1) arow = 2 * arow - (arow & 15) + 16;
      gl2lds16(A + arow * (long)K + k0 + k8l * 8, ldsA);
      gl2lds16(W + (long)(n0 + r) * K + k0 + k8l * 8, ldsB);
    }
    __syncthreads();
    b16x8 af[4], bfr[4];
#pragma unroll
    for (int i = 0; i < 4; i++) af[i] = *(const b16x8*)(As + sw_off(wr * 64 + i * 16 + lm, l8));
#pragma unroll
    for (int j = 0; j < 4; j++) bfr[j] = *(const b16x8*)(Bs + sw_off(wc * 64 + j * 16 + lm, l8));
#pragma unroll
    for (int i = 0; i < 4; i++)
#pragma unroll
      for (int j = 0; j < 4; j++)
        acc[i][j] = __builtin_amdgcn_mfma_f32_16x16x32_bf16(af[i], bfr[j], acc[i][j], 0, 0, 0);
    __syncthreads();
  }

  if (MODE == 0) {
    const bool is_delta = (n0 < H_DIM);
    const float* bias = is_delta ? bias0 : bias1;
    b16* ob = is_delta ? ob0 : ob1;
    const int nc0 = (n0 & (H_DIM - 1)) + wc * 64 + lm;
    float bv[4];
#pragma unroll
    for (int j = 0; j < 4; j++) bv[j] = bias[nc0 + j * 16];
#pragma unroll
    for (int i = 0; i < 4; i++) {
      const long rb = m0 + wr * 64 + i * 16 + l8 * 4;
      b16* pr = ob + rb * H_DIM + nc0;
      if (is_delta) {
#pragma unroll
        for (int j = 0; j < 4; j++)
#pragma unroll
          for (int rg = 0; rg < 4; ++rg)
            pr[(long)rg * H_DIM + j * 16] = (b16)softplus_fast(acc[i][j][rg] + bv[j]);
      } else {
#pragma unroll
        for (int j = 0; j < 4; j++)
#pragma unroll
          for (int rg = 0; rg < 4; ++rg)
            pr[(long)rg * H_DIM + j * 16] = (b16)(acc[i][j][rg] + bv[j]);
      }
    }
  } else if (MODE == 1) {
    const int nc0 = n0 + wc * 64 + lm;
#pragma unroll
    for (int i = 0; i < 4; i++) {
      const long rb = m0 + wr * 64 + i * 16 + l8 * 4;
      const b16* hp = hsel + rb * H_DIM + nc0;
      b16* pr = ob0 + rb * H_DIM + nc0;
#pragma unroll
      for (int j = 0; j < 4; j++)
#pragma unroll
        for (int rg = 0; rg < 4; ++rg) {
          float hv = (float)hp[(long)rg * H_DIM + j * 16];
          pr[(long)rg * H_DIM + j * 16] = (b16)(acc[i][j][rg] * hv);
        }
    }
  } else {
    const int nc0 = n0 + wc * 64 + lm;
    float bv[4];
#pragma unroll
    for (int j = 0; j < 4; j++) bv[j] = bias0[nc0 + j * 16];
#pragma unroll
    for (int i = 0; i < 4; i++) {
      const long rb = m0 + wr * 64 + i * 16 + l8 * 4;
      float* pr = of + rb * D_INP + nc0;
#pragma unroll
      for (int j = 0; j < 4; j++)
#pragma unroll
        for (int rg = 0; rg < 4; ++rg)
          pr[(long)rg * D_INP + j * 16] = acc[i][j][rg] + bv[j];
    }
  }
}

// ---------------------------------------------------------------------------
// Chunked-scan recurrence: h_t = (1-d_t) h_{t-1} + d_t u_t.
// Vectorized: each thread owns 8 consecutive h-columns -> b16x8 (16B/lane).
// unroll 4 for memory-level parallelism (Little's law at ~900cy HBM latency).
// ---------------------------------------------------------------------------
__global__ void scan_a_kernel(const b16* __restrict__ dl, const b16* __restrict__ uu,
                              float* __restrict__ P, float* __restrict__ Q) {
  int g = blockIdx.x * 256 + threadIdx.x;   // [0, NC*BH8)
  int c = g >> 12;                           // BH8 = 4096
  int p = g & (BH8 - 1);
  const b16x8* dp = (const b16x8*)dl + (size_t)c * CS * BH8 + p;
  const b16x8* up = (const b16x8*)uu + (size_t)c * CS * BH8 + p;
  float h[8], pr[8];
#pragma unroll
  for (int e = 0; e < 8; ++e) { h[e] = 0.f; pr[e] = 1.f; }
#pragma unroll 4
  for (int s = 0; s < CS; ++s) {
    b16x8 dv = dp[(size_t)s * BH8];
    b16x8 uv = up[(size_t)s * BH8];
#pragma unroll
    for (int e = 0; e < 8; ++e) {
      float d = (float)dv[e], u = (float)uv[e];
      float a = 1.f - d;
      h[e] = a * h[e] + d * u;
      pr[e] *= a;
    }
  }
  ((f32x4*)P)[g * 2 + 0] = {pr[0], pr[1], pr[2], pr[3]};
  ((f32x4*)P)[g * 2 + 1] = {pr[4], pr[5], pr[6], pr[7]};
  ((f32x4*)Q)[g * 2 + 0] = {h[0], h[1], h[2], h[3]};
  ((f32x4*)Q)[g * 2 + 1] = {h[4], h[5], h[6], h[7]};
}

__global__ void scan_b_kernel(const float* __restrict__ P, const float* __restrict__ Q,
                              float* __restrict__ Hs) {
  int p = blockIdx.x * 256 + threadIdx.x;  // [0, BH)
  float h = 0.f;
#pragma unroll
  for (int c = 0; c < NC; ++c) {
    Hs[c * BH + p] = h;
    h = P[c * BH + p] * h + Q[c * BH + p];
  }
}

__global__ void scan_c_kernel(const b16* __restrict__ dl, const b16* __restrict__ uu,
                              const float* __restrict__ Hs, b16* __restrict__ hsel) {
  int g = blockIdx.x * 256 + threadIdx.x;
  int c = g >> 12;
  int p = g & (BH8 - 1);
  const b16x8* dp = (const b16x8*)dl + (size_t)c * CS * BH8 + p;
  const b16x8* up = (const b16x8*)uu + (size_t)c * CS * BH8 + p;
  b16x8* hp = (b16x8*)hsel + (size_t)c * (CS / 2) * BH8 + p;
  f32x4 h0a = ((const f32x4*)(Hs + (size_t)c * BH))[p * 2];
  f32x4 h0b = ((const f32x4*)(Hs + (size_t)c * BH))[p * 2 + 1];
  float h[8] = {h0a[0], h0a[1], h0a[2], h0a[3], h0b[0], h0b[1], h0b[2], h0b[3]};
#pragma unroll 4
  for (int s = 0; s < CS; ++s) {
    b16x8 dv = dp[(size_t)s * BH8];
    b16x8 uv = up[(size_t)s * BH8];
#pragma unroll
    for (int e = 0; e < 8; ++e) {
      float d = (float)dv[e], u = (float)uv[e];
      h[e] = (1.f - d) * h[e] + d * u;
    }
    if (s & 1) {
      b16x8 o = {(b16)h[0], (b16)h[1], (b16)h[2], (b16)h[3],
                 (b16)h[4], (b16)h[5], (b16)h[6], (b16)h[7]};
      hp[(size_t)(s >> 1) * BH8] = o;
    }
  }
}

// ---------------------------------------------------------------------------
extern "C" void kernel_launch(void* const* d_in, const int* in_sizes, int n_in,
                              void* d_out, int out_size, void* d_ws, size_t ws_size,
                              hipStream_t stream) {
  const float* x   = (const float*)d_in[0];
  // d_in[1] = A (unused by the reference forward)
  const float* WB  = (const float*)d_in[2];
  const float* Wc  = (const float*)d_in[3];
  const float* Wd  = (const float*)d_in[4];
  const float* bd  = (const float*)d_in[5];
  const float* Win = (const float*)d_in[6];
  const float* bi  = (const float*)d_in[7];
  const float* Wcp = (const float*)d_in[8];
  const float* bc  = (const float*)d_in[9];
  float* out = (float*)d_out;

  char* w = (char*)d_ws;
  size_t off = 0;
  auto alloc = [&](size_t bytes) {
    void* p = w + off;
    off += (bytes + 255) & ~(size_t)255;
    return p;
  };
  b16* xb   = (b16*)alloc((size_t)S_LEN * BATCH * D_INP * 2);
  b16* Wdu  = (b16*)alloc((size_t)2 * H_DIM * D_INP * 2);
  b16* Wcb  = (b16*)alloc((size_t)H_DIM * D_INP * 2);
  b16* Wcpb = (b16*)alloc((size_t)D_INP * H_DIM * 2);
  b16* dbuf = (b16*)alloc((size_t)S_LEN * BH * 2);
  b16* ubuf = (b16*)alloc((size_t)S_LEN * BH * 2);
  b16* hsel = (b16*)alloc((size_t)SC * BH * 2);
  b16* ysel = (b16*)alloc((size_t)SC * BH * 2);
  float* P  = (float*)alloc((size_t)NC * BH * 4);
  float* Q  = (float*)alloc((size_t)NC * BH * 4);
  float* Hs = (float*)alloc((size_t)NC * BH * 4);
  if (off > ws_size) {
    fprintf(stderr, "kernel_launch: ws too small: need %zu have %zu\n", off, ws_size);
    return;
  }

  // One-time opt-in to 128 KB dynamic LDS for the 8-phase kernels.
  static int g_big = -1;
  if (g_big < 0) {
    hipError_t e0 = hipFuncSetAttribute(reinterpret_cast<const void*>(&gemm8p<0>),
                                        hipFuncAttributeMaxDynamicSharedMemorySize, 131072);
    hipError_t e1 = hipFuncSetAttribute(reinterpret_cast<const void*>(&gemm8p<1>),
                                        hipFuncAttributeMaxDynamicSharedMemorySize, 131072);
    hipError_t e2 = hipFuncSetAttribute(reinterpret_cast<const void*>(&gemm8p<2>),
                                        hipFuncAttributeMaxDynamicSharedMemorySize, 131072);
    g_big = (e0 == hipSuccess && e1 == hipSuccess && e2 == hipSuccess) ? 1 : 0;
  }

  // 1) x -> bf16
  int n8 = S_LEN * BATCH * D_INP / 8;
  cvt_x_kernel<<<(n8 + 255) / 256, 256, 0, stream>>>(x, xb, n8);
  // 2) weights -> bf16 (+ W_in+W_B fold)
  int hd4 = H_DIM * D_INP / 4;
  prep_w_kernel<<<(hd4 + 255) / 256, 256, 0, stream>>>(Wd, Win, WB, Wc, Wcp, Wdu, Wcb, Wcpb);
  // 3) delta/u projections: M=32768, N=4096, K=1024
  if (g_big) {
    dim3 g1(2 * H_DIM / 256, S_LEN * BATCH / 256);  // 16 x 128 = 2048 blocks
    gemm8p<0><<<g1, 512, 131072, stream>>>(xb, Wdu, D_INP, bd, bi, nullptr, dbuf, ubuf, nullptr);
  } else {
    dim3 g1(2 * H_DIM / 128, S_LEN * BATCH / 128);
    gemm_bt<0><<<g1, 256, 0, stream>>>(xb, Wdu, D_INP, bd, bi, nullptr, dbuf, ubuf, nullptr);
  }
  // 4-6) chunked scan over S (vectorized 8 cols/thread)
  scan_a_kernel<<<NC * BH8 / 256, 256, 0, stream>>>(dbuf, ubuf, P, Q);
  scan_b_kernel<<<BH / 256, 256, 0, stream>>>(P, Q, Hs);
  scan_c_kernel<<<NC * BH8 / 256, 256, 0, stream>>>(dbuf, ubuf, Hs, hsel);
  // 7) C projection at odd timesteps, fused *h: M=16384, N=2048, K=1024
  if (g_big) {
    dim3 g2(H_DIM / 256, SC * BATCH / 256);  // 8 x 64 = 512 blocks
    gemm8p<1><<<g2, 512, 131072, stream>>>(xb, Wcb, D_INP, nullptr, nullptr, hsel, ysel, nullptr, nullptr);
  } else {
    dim3 g2(H_DIM / 128, SC * BATCH / 128);
    gemm_bt<1><<<g2, 256, 0, stream>>>(xb, Wcb, D_INP, nullptr, nullptr, hsel, ysel, nullptr, nullptr);
  }
  // 8) compress: M=16384, N=1024, K=2048, fp32 out + b_comp
  if (g_big) {
    dim3 g3(D_INP / 256, SC * BATCH / 256);  // 4 x 64 = 256 blocks
    gemm8p<2><<<g3, 512, 131072, stream>>>(ysel, Wcpb, H_DIM, bc, nullptr, nullptr, nullptr, nullptr, out);
  } else {
    dim3 g3(D_INP / 128, SC * BATCH / 128);
    gemm_bt<2><<<g3, 256, 0, stream>>>(ysel, Wcpb, H_DIM, bc, nullptr, nullptr, nullptr, nullptr, out);
  }
}

// Round 5
// 826.164 us; speedup vs baseline: 1.1234x; 1.1234x over previous
//
#include <hip/hip_runtime.h>
#include <hip/hip_bf16.h>
#include <cstdio>

// Problem constants (S6HistoryCompressor)
#define S_LEN 2048
#define BATCH 16
#define D_INP 1024
#define H_DIM 2048
#define SC    (S_LEN / 2)       // compressed length (step=2, rows 1,3,...,2047)
#define BH    (BATCH * H_DIM)   // 32768 independent recurrences
#define BH8   (BH / 8)          // 4096 vectorized lanes
#define NC    64                // scan chunks (64 -> 1024-block scan grids)
#define CS    (S_LEN / NC)      // 32 steps per chunk

typedef __bf16 b16;
typedef __bf16 b16x8 __attribute__((ext_vector_type(8)));
typedef __bf16 b16x4 __attribute__((ext_vector_type(4)));
typedef float  f32x4 __attribute__((ext_vector_type(4)));

// XOR swizzle for LDS sub-tile [256 rows][32 bf16 cols], 16B granules.
// Physical slot p in row r holds LOGICAL granule p ^ ((r>>1)&3).
// Frag reads (lanes 0-15 = rows, l8 = granule) hit 2-way (free) aliasing only.
__device__ __forceinline__ int sw_off(int r, int k8) {
  return r * 32 + ((k8 ^ ((r >> 1) & 3)) << 3);
}

// Async global -> LDS, 16 B per lane. LDS dest = wave-uniform base + lane*16
// (hardware rule, m104/m108); swizzle is applied on the GLOBAL address side.
__device__ __forceinline__ void gl2lds16(const b16* g, b16* l) {
  __builtin_amdgcn_global_load_lds(
      (const __attribute__((address_space(1))) void*)g,
      (__attribute__((address_space(3))) void*)l, 16, 0, 0);
}

// Fast branchless softplus: log(1+e^t) = max(t,0) + log(1+e^-|t|).
__device__ __forceinline__ float softplus_fast(float t) {
  float e = __expf(-fabsf(t));
  return fmaxf(t, 0.f) + __logf(1.f + e);
}

// ---------------------------------------------------------------------------
// Conversions (vectorized: 16B/lane stores)
// ---------------------------------------------------------------------------
__global__ void cvt_x_kernel(const float* __restrict__ in, b16* __restrict__ out, int n8) {
  int i = blockIdx.x * 256 + threadIdx.x;
  if (i >= n8) return;
  float4 v0 = ((const float4*)in)[i * 2];
  float4 v1 = ((const float4*)in)[i * 2 + 1];
  b16x8 o = {(b16)v0.x, (b16)v0.y, (b16)v0.z, (b16)v0.w,
             (b16)v1.x, (b16)v1.y, (b16)v1.z, (b16)v1.w};
  ((b16x8*)out)[i] = o;
}

__global__ void prep_w_kernel(const float* __restrict__ Wd, const float* __restrict__ Win,
                              const float* __restrict__ WB, const float* __restrict__ Wc,
                              const float* __restrict__ Wcp,
                              b16* __restrict__ Wdu, b16* __restrict__ Wcb,
                              b16* __restrict__ Wcpb) {
  const int HD4 = (H_DIM * D_INP) / 4;
  int i = blockIdx.x * 256 + threadIdx.x;
  if (i >= HD4) return;
  float4 a = ((const float4*)Wd)[i];
  float4 b = ((const float4*)Win)[i];
  float4 c = ((const float4*)WB)[i];
  float4 d = ((const float4*)Wc)[i];
  float4 e = ((const float4*)Wcp)[i];
  ((b16x4*)Wdu)[i] = {(b16)a.x, (b16)a.y, (b16)a.z, (b16)a.w};
  ((b16x4*)Wdu)[HD4 + i] = {(b16)(b.x + c.x), (b16)(b.y + c.y), (b16)(b.z + c.z), (b16)(b.w + c.w)};
  ((b16x4*)Wcb)[i] = {(b16)d.x, (b16)d.y, (b16)d.z, (b16)d.w};
  ((b16x4*)Wcpb)[i] = {(b16)e.x, (b16)e.y, (b16)e.z, (b16)e.w};
}

// ---------------------------------------------------------------------------
// 8-phase 256x256 GEMM (best-measured variant, R2 = 323 us on gemm<0>).
// C = A[M,K] x W[N,K]^T, bf16. 8 waves (512 thr), per-wave 128x64
// (acc[8][4]), BK=64. LDS: 2 x 64 KB buffers = Ah0|Ah1|Bh0|Bh1 sub-tiles.
// ---------------------------------------------------------------------------
#define AH0 0
#define AH1 8192
#define BH0 16384
#define BH1 24576

template <int MODE>
__device__ __forceinline__ void stage_half(const b16* __restrict__ G, int ldg,
                                           int base_row, int kcol, b16* half_base,
                                           int wave, int lane, bool isA) {
#pragma unroll
  for (int q = 0; q < 2; ++q) {
    const int rbase = q * 128 + wave * 16;      // 16-row stripe (wave-uniform)
    const int r = rbase + (lane >> 2);          // row 0..255
    const int p = lane & 3;                     // physical granule
    const int gl = p ^ ((r >> 1) & 3);          // logical granule to fetch
    long grow = base_row + r;
    if (MODE == 1 && isA) grow = 2 * grow - (grow & 15) + 16;  // odd-t remap
    gl2lds16(G + grow * (long)ldg + kcol + gl * 8, half_base + rbase * 32);
  }
}

template <int MODE>
__global__ __launch_bounds__(512, 2) void gemm8p(
    const b16* __restrict__ A, const b16* __restrict__ W, int K,
    const float* __restrict__ bias0, const float* __restrict__ bias1,
    const b16* __restrict__ hsel, b16* __restrict__ ob0, b16* __restrict__ ob1,
    float* __restrict__ of) {
  extern __shared__ b16 lds[];  // 2 x 32768 b16 = 128 KB
  const int tid  = threadIdx.x;
  const int lane = tid & 63;
  const int wave = tid >> 6;
  const int wm = wave >> 2, wn = wave & 3;
  const int lm = lane & 15;
  const int l8 = lane >> 4;

  // Bijective XCD swizzle (all grids have nwg % 8 == 0).
  const int gx  = gridDim.x;
  const int nwg = gx * gridDim.y;
  const int id0 = blockIdx.y * gx + blockIdx.x;
  const int sw  = (id0 & 7) * (nwg >> 3) + (id0 >> 3);
  const int m0 = (sw / gx) * 256;
  const int n0 = (sw % gx) * 256;

  f32x4 acc[8][4];
#pragma unroll
  for (int i = 0; i < 8; i++)
#pragma unroll
    for (int j = 0; j < 4; j++) acc[i][j] = (f32x4)0.f;

  const int NT = K >> 6;  // BK=64 tiles

  // Prologue: stage tile 0 (Ah0, Bh0 first -- they gate P0).
  {
    b16* B0 = lds;
    stage_half<MODE>(A, K, m0, 0,  B0 + AH0, wave, lane, true);
    stage_half<MODE>(W, K, n0, 0,  B0 + BH0, wave, lane, false);
    stage_half<MODE>(A, K, m0, 32, B0 + AH1, wave, lane, true);
    stage_half<MODE>(W, K, n0, 32, B0 + BH1, wave, lane, false);
    asm volatile("s_waitcnt vmcnt(4)" ::: "memory");  // Ah0,Bh0 landed
    __builtin_amdgcn_s_barrier();
  }

  for (int t = 0; t < NT; ++t) {
    b16* const C = lds + ((t & 1) << 15);
    b16* const N = lds + (((t + 1) & 1) << 15);
    const int kn = (t + 1) << 6;
    const bool pf = (t + 1 < NT);
    b16x8 a[8], bb0, bb1;

    // ---- P0: ks=0, j in {0,1} ------------------------------------------
#pragma unroll
    for (int i = 0; i < 8; i++)
      a[i] = *(const b16x8*)(C + AH0 + sw_off(wm * 128 + i * 16 + lm, l8));
    bb0 = *(const b16x8*)(C + BH0 + sw_off(wn * 64 + 0 + lm, l8));
    bb1 = *(const b16x8*)(C + BH0 + sw_off(wn * 64 + 16 + lm, l8));
    if (pf) stage_half<MODE>(A, K, m0, kn, N + AH0, wave, lane, true);
    __builtin_amdgcn_s_barrier();
    asm volatile("s_waitcnt lgkmcnt(0)" ::: "memory");
    __builtin_amdgcn_sched_barrier(0);
    __builtin_amdgcn_s_setprio(1);
#pragma unroll
    for (int i = 0; i < 8; i++) {
      acc[i][0] = __builtin_amdgcn_mfma_f32_16x16x32_bf16(a[i], bb0, acc[i][0], 0, 0, 0);
      acc[i][1] = __builtin_amdgcn_mfma_f32_16x16x32_bf16(a[i], bb1, acc[i][1], 0, 0, 0);
    }
    __builtin_amdgcn_s_setprio(0);
    __builtin_amdgcn_s_barrier();

    // ---- P1: ks=0, j in {2,3}; vmcnt gates Ah1(t)/Bh1(t) ----------------
    bb0 = *(const b16x8*)(C + BH0 + sw_off(wn * 64 + 32 + lm, l8));
    bb1 = *(const b16x8*)(C + BH0 + sw_off(wn * 64 + 48 + lm, l8));
    if (pf) {
      stage_half<MODE>(W, K, n0, kn, N + BH0, wave, lane, false);
      asm volatile("s_waitcnt vmcnt(4)" ::: "memory");
    } else {
      asm volatile("s_waitcnt vmcnt(0)" ::: "memory");
    }
    __builtin_amdgcn_s_barrier();
    asm volatile("s_waitcnt lgkmcnt(0)" ::: "memory");
    __builtin_amdgcn_sched_barrier(0);
    __builtin_amdgcn_s_setprio(1);
#pragma unroll
    for (int i = 0; i < 8; i++) {
      acc[i][2] = __builtin_amdgcn_mfma_f32_16x16x32_bf16(a[i], bb0, acc[i][2], 0, 0, 0);
      acc[i][3] = __builtin_amdgcn_mfma_f32_16x16x32_bf16(a[i], bb1, acc[i][3], 0, 0, 0);
    }
    __builtin_amdgcn_s_setprio(0);
    __builtin_amdgcn_s_barrier();

    // ---- P2: ks=1, j in {0,1} ------------------------------------------
#pragma unroll
    for (int i = 0; i < 8; i++)
      a[i] = *(const b16x8*)(C + AH1 + sw_off(wm * 128 + i * 16 + lm, l8));
    bb0 = *(const b16x8*)(C + BH1 + sw_off(wn * 64 + 0 + lm, l8));
    bb1 = *(const b16x8*)(C + BH1 + sw_off(wn * 64 + 16 + lm, l8));
    if (pf) stage_half<MODE>(A, K, m0, kn + 32, N + AH1, wave, lane, true);
    __builtin_amdgcn_s_barrier();
    asm volatile("s_waitcnt lgkmcnt(0)" ::: "memory");
    __builtin_amdgcn_sched_barrier(0);
    __builtin_amdgcn_s_setprio(1);
#pragma unroll
    for (int i = 0; i < 8; i++) {
      acc[i][0] = __builtin_amdgcn_mfma_f32_16x16x32_bf16(a[i], bb0, acc[i][0], 0, 0, 0);
      acc[i][1] = __builtin_amdgcn_mfma_f32_16x16x32_bf16(a[i], bb1, acc[i][1], 0, 0, 0);
    }
    __builtin_amdgcn_s_setprio(0);
    __builtin_amdgcn_s_barrier();

    // ---- P3: ks=1, j in {2,3}; vmcnt gates Ah0(t+1)/Bh0(t+1) ------------
    bb0 = *(const b16x8*)(C + BH1 + sw_off(wn * 64 + 32 + lm, l8));
    bb1 = *(const b16x8*)(C + BH1 + sw_off(wn * 64 + 48 + lm, l8));
    if (pf) {
      stage_half<MODE>(W, K, n0, kn + 32, N + BH1, wave, lane, false);
      asm volatile("s_waitcnt vmcnt(4)" ::: "memory");
    }
    __builtin_amdgcn_s_barrier();
    asm volatile("s_waitcnt lgkmcnt(0)" ::: "memory");
    __builtin_amdgcn_sched_barrier(0);
    __builtin_amdgcn_s_setprio(1);
#pragma unroll
    for (int i = 0; i < 8; i++) {
      acc[i][2] = __builtin_amdgcn_mfma_f32_16x16x32_bf16(a[i], bb0, acc[i][2], 0, 0, 0);
      acc[i][3] = __builtin_amdgcn_mfma_f32_16x16x32_bf16(a[i], bb1, acc[i][3], 0, 0, 0);
    }
    __builtin_amdgcn_s_setprio(0);
    __builtin_amdgcn_s_barrier();
  }

  // Epilogue. C/D layout: col = lane&15, row = (lane>>4)*4 + reg [m89/m91].
  if (MODE == 0) {
    const bool is_delta = (n0 < H_DIM);  // block-uniform (gx=16, 8+8 split)
    const float* bias = is_delta ? bias0 : bias1;
    b16* ob = is_delta ? ob0 : ob1;
    const int nc0 = (n0 & (H_DIM - 1)) + wn * 64 + lm;
    float bv[4];
#pragma unroll
    for (int j = 0; j < 4; j++) bv[j] = bias[nc0 + j * 16];
#pragma unroll
    for (int i = 0; i < 8; i++) {
      const long rb = m0 + wm * 128 + i * 16 + l8 * 4;
      b16* pr = ob + rb * H_DIM + nc0;
      if (is_delta) {
#pragma unroll
        for (int j = 0; j < 4; j++)
#pragma unroll
          for (int rg = 0; rg < 4; ++rg)
            pr[(long)rg * H_DIM + j * 16] = (b16)softplus_fast(acc[i][j][rg] + bv[j]);
      } else {
#pragma unroll
        for (int j = 0; j < 4; j++)
#pragma unroll
          for (int rg = 0; rg < 4; ++rg)
            pr[(long)rg * H_DIM + j * 16] = (b16)(acc[i][j][rg] + bv[j]);
      }
    }
  } else if (MODE == 1) {
    const int nc0 = n0 + wn * 64 + lm;
#pragma unroll
    for (int i = 0; i < 8; i++) {
      const long rb = m0 + wm * 128 + i * 16 + l8 * 4;
      const b16* hp = hsel + rb * H_DIM + nc0;
      b16* pr = ob0 + rb * H_DIM + nc0;
#pragma unroll
      for (int j = 0; j < 4; j++)
#pragma unroll
        for (int rg = 0; rg < 4; ++rg) {
          float hv = (float)hp[(long)rg * H_DIM + j * 16];
          pr[(long)rg * H_DIM + j * 16] = (b16)(acc[i][j][rg] * hv);
        }
    }
  } else {
    const int nc0 = n0 + wn * 64 + lm;
    float bv[4];
#pragma unroll
    for (int j = 0; j < 4; j++) bv[j] = bias0[nc0 + j * 16];
#pragma unroll
    for (int i = 0; i < 8; i++) {
      const long rb = m0 + wm * 128 + i * 16 + l8 * 4;
      float* pr = of + rb * D_INP + nc0;
#pragma unroll
      for (int j = 0; j < 4; j++)
#pragma unroll
        for (int rg = 0; rg < 4; ++rg)
          pr[(long)rg * D_INP + j * 16] = acc[i][j][rg] + bv[j];
    }
  }
}

// ---------------------------------------------------------------------------
// Fallback: 128x128 kernel (used only if 128 KB dynamic LDS opt-in refused).
// ---------------------------------------------------------------------------
template <int MODE>
__global__ __launch_bounds__(256, 2) void gemm_bt(
    const b16* __restrict__ A, const b16* __restrict__ W, int K,
    const float* __restrict__ bias0, const float* __restrict__ bias1,
    const b16* __restrict__ hsel, b16* __restrict__ ob0, b16* __restrict__ ob1,
    float* __restrict__ of) {
  __shared__ b16 As[128 * 32];
  __shared__ b16 Bs[128 * 32];
  const int tid  = threadIdx.x;
  const int lane = tid & 63;
  const int wave = tid >> 6;
  const int wr = wave >> 1, wc = wave & 1;
  const int m0 = blockIdx.y * 128;
  const int n0 = blockIdx.x * 128;
  const int lm = lane & 15;
  const int l8 = lane >> 4;
  const int rL  = wave * 16 + (lane >> 2);
  const int k8p = lane & 3;

  f32x4 acc[4][4];
#pragma unroll
  for (int i = 0; i < 4; i++)
#pragma unroll
    for (int j = 0; j < 4; j++) acc[i][j] = (f32x4)0.f;

  for (int k0 = 0; k0 < K; k0 += 32) {
#pragma unroll
    for (int hh = 0; hh < 2; ++hh) {
      const int r = rL + hh * 64;
      const int k8l = k8p ^ ((r >> 1) & 3);
      b16* ldsA = As + (wave * 16 + hh * 64) * 32;
      b16* ldsB = Bs + (wave * 16 + hh * 64) * 32;
      long arow = m0 + r;
      if (MODE == 1) arow = 2 * arow - (arow & 15) + 16;
      gl2lds16(A + arow * (long)K + k0 + k8l * 8, ldsA);
      gl2lds16(W + (long)(n0 + r) * K + k0 + k8l * 8, ldsB);
    }
    __syncthreads();
    b16x8 af[4], bfr[4];
#pragma unroll
    for (int i = 0; i < 4; i++) af[i] = *(const b16x8*)(As + sw_off(wr * 64 + i * 16 + lm, l8));
#pragma unroll
    for (int j = 0; j < 4; j++) bfr[j] = *(const b16x8*)(Bs + sw_off(wc * 64 + j * 16 + lm, l8));
#pragma unroll
    for (int i = 0; i < 4; i++)
#pragma unroll
      for (int j = 0; j < 4; j++)
        acc[i][j] = __builtin_amdgcn_mfma_f32_16x16x32_bf16(af[i], bfr[j], acc[i][j], 0, 0, 0);
    __syncthreads();
  }

  if (MODE == 0) {
    const bool is_delta = (n0 < H_DIM);
    const float* bias = is_delta ? bias0 : bias1;
    b16* ob = is_delta ? ob0 : ob1;
    const int nc0 = (n0 & (H_DIM - 1)) + wc * 64 + lm;
    float bv[4];
#pragma unroll
    for (int j = 0; j < 4; j++) bv[j] = bias[nc0 + j * 16];
#pragma unroll
    for (int i = 0; i < 4; i++) {
      const long rb = m0 + wr * 64 + i * 16 + l8 * 4;
      b16* pr = ob + rb * H_DIM + nc0;
      if (is_delta) {
#pragma unroll
        for (int j = 0; j < 4; j++)
#pragma unroll
          for (int rg = 0; rg < 4; ++rg)
            pr[(long)rg * H_DIM + j * 16] = (b16)softplus_fast(acc[i][j][rg] + bv[j]);
      } else {
#pragma unroll
        for (int j = 0; j < 4; j++)
#pragma unroll
          for (int rg = 0; rg < 4; ++rg)
            pr[(long)rg * H_DIM + j * 16] = (b16)(acc[i][j][rg] + bv[j]);
      }
    }
  } else if (MODE == 1) {
    const int nc0 = n0 + wc * 64 + lm;
#pragma unroll
    for (int i = 0; i < 4; i++) {
      const long rb = m0 + wr * 64 + i * 16 + l8 * 4;
      const b16* hp = hsel + rb * H_DIM + nc0;
      b16* pr = ob0 + rb * H_DIM + nc0;
#pragma unroll
      for (int j = 0; j < 4; j++)
#pragma unroll
        for (int rg = 0; rg < 4; ++rg) {
          float hv = (float)hp[(long)rg * H_DIM + j * 16];
          pr[(long)rg * H_DIM + j * 16] = (b16)(acc[i][j][rg] * hv);
        }
    }
  } else {
    const int nc0 = n0 + wc * 64 + lm;
    float bv[4];
#pragma unroll
    for (int j = 0; j < 4; j++) bv[j] = bias0[nc0 + j * 16];
#pragma unroll
    for (int i = 0; i < 4; i++) {
      const long rb = m0 + wr * 64 + i * 16 + l8 * 4;
      float* pr = of + rb * D_INP + nc0;
#pragma unroll
      for (int j = 0; j < 4; j++)
#pragma unroll
        for (int rg = 0; rg < 4; ++rg)
          pr[(long)rg * D_INP + j * 16] = acc[i][j][rg] + bv[j];
    }
  }
}

// ---------------------------------------------------------------------------
// Chunked-scan recurrence: h_t = (1-d_t) h_{t-1} + d_t u_t.
// b16x8 (16B/lane) loads + NC=64 chunks -> 1024-block grids (4 blocks/CU)
// so TLP covers HBM latency (R3/R4's 256-block grids were latency-starved).
// ---------------------------------------------------------------------------
__global__ void scan_a_kernel(const b16* __restrict__ dl, const b16* __restrict__ uu,
                              float* __restrict__ P, float* __restrict__ Q) {
  int g = blockIdx.x * 256 + threadIdx.x;   // [0, NC*BH8)
  int c = g >> 12;                           // BH8 = 4096
  int p = g & (BH8 - 1);
  const b16x8* dp = (const b16x8*)dl + (size_t)c * CS * BH8 + p;
  const b16x8* up = (const b16x8*)uu + (size_t)c * CS * BH8 + p;
  float h[8], pr[8];
#pragma unroll
  for (int e = 0; e < 8; ++e) { h[e] = 0.f; pr[e] = 1.f; }
#pragma unroll 2
  for (int s = 0; s < CS; ++s) {
    b16x8 dv = dp[(size_t)s * BH8];
    b16x8 uv = up[(size_t)s * BH8];
#pragma unroll
    for (int e = 0; e < 8; ++e) {
      float d = (float)dv[e], u = (float)uv[e];
      float a = 1.f - d;
      h[e] = a * h[e] + d * u;
      pr[e] *= a;
    }
  }
  ((f32x4*)P)[g * 2 + 0] = {pr[0], pr[1], pr[2], pr[3]};
  ((f32x4*)P)[g * 2 + 1] = {pr[4], pr[5], pr[6], pr[7]};
  ((f32x4*)Q)[g * 2 + 0] = {h[0], h[1], h[2], h[3]};
  ((f32x4*)Q)[g * 2 + 1] = {h[4], h[5], h[6], h[7]};
}

__global__ void scan_b_kernel(const float* __restrict__ P, const float* __restrict__ Q,
                              float* __restrict__ Hs) {
  int p = blockIdx.x * 256 + threadIdx.x;  // [0, BH)
  float h = 0.f;
#pragma unroll 4
  for (int c = 0; c < NC; ++c) {
    Hs[c * BH + p] = h;
    h = P[c * BH + p] * h + Q[c * BH + p];
  }
}

__global__ void scan_c_kernel(const b16* __restrict__ dl, const b16* __restrict__ uu,
                              const float* __restrict__ Hs, b16* __restrict__ hsel) {
  int g = blockIdx.x * 256 + threadIdx.x;
  int c = g >> 12;
  int p = g & (BH8 - 1);
  const b16x8* dp = (const b16x8*)dl + (size_t)c * CS * BH8 + p;
  const b16x8* up = (const b16x8*)uu + (size_t)c * CS * BH8 + p;
  b16x8* hp = (b16x8*)hsel + (size_t)c * (CS / 2) * BH8 + p;
  f32x4 h0a = ((const f32x4*)(Hs + (size_t)c * BH))[p * 2];
  f32x4 h0b = ((const f32x4*)(Hs + (size_t)c * BH))[p * 2 + 1];
  float h[8] = {h0a[0], h0a[1], h0a[2], h0a[3], h0b[0], h0b[1], h0b[2], h0b[3]};
#pragma unroll 2
  for (int s = 0; s < CS; ++s) {
    b16x8 dv = dp[(size_t)s * BH8];
    b16x8 uv = up[(size_t)s * BH8];
#pragma unroll
    for (int e = 0; e < 8; ++e) {
      float d = (float)dv[e], u = (float)uv[e];
      h[e] = (1.f - d) * h[e] + d * u;
    }
    if (s & 1) {
      b16x8 o = {(b16)h[0], (b16)h[1], (b16)h[2], (b16)h[3],
                 (b16)h[4], (b16)h[5], (b16)h[6], (b16)h[7]};
      hp[(size_t)(s >> 1) * BH8] = o;
    }
  }
}

// ---------------------------------------------------------------------------
extern "C" void kernel_launch(void* const* d_in, const int* in_sizes, int n_in,
                              void* d_out, int out_size, void* d_ws, size_t ws_size,
                              hipStream_t stream) {
  const float* x   = (const float*)d_in[0];
  // d_in[1] = A (unused by the reference forward)
  const float* WB  = (const float*)d_in[2];
  const float* Wc  = (const float*)d_in[3];
  const float* Wd  = (const float*)d_in[4];
  const float* bd  = (const float*)d_in[5];
  const float* Win = (const float*)d_in[6];
  const float* bi  = (const float*)d_in[7];
  const float* Wcp = (const float*)d_in[8];
  const float* bc  = (const float*)d_in[9];
  float* out = (float*)d_out;

  char* w = (char*)d_ws;
  size_t off = 0;
  auto alloc = [&](size_t bytes) {
    void* p = w + off;
    off += (bytes + 255) & ~(size_t)255;
    return p;
  };
  b16* xb   = (b16*)alloc((size_t)S_LEN * BATCH * D_INP * 2);
  b16* Wdu  = (b16*)alloc((size_t)2 * H_DIM * D_INP * 2);
  b16* Wcb  = (b16*)alloc((size_t)H_DIM * D_INP * 2);
  b16* Wcpb = (b16*)alloc((size_t)D_INP * H_DIM * 2);
  b16* dbuf = (b16*)alloc((size_t)S_LEN * BH * 2);
  b16* ubuf = (b16*)alloc((size_t)S_LEN * BH * 2);
  b16* hsel = (b16*)alloc((size_t)SC * BH * 2);
  b16* ysel = (b16*)alloc((size_t)SC * BH * 2);
  float* P  = (float*)alloc((size_t)NC * BH * 4);
  float* Q  = (float*)alloc((size_t)NC * BH * 4);
  float* Hs = (float*)alloc((size_t)NC * BH * 4);
  if (off > ws_size) {
    fprintf(stderr, "kernel_launch: ws too small: need %zu have %zu\n", off, ws_size);
    return;
  }

  // One-time opt-in to 128 KB dynamic LDS for the 8-phase kernels.
  static int g_big = -1;
  if (g_big < 0) {
    hipError_t e0 = hipFuncSetAttribute(reinterpret_cast<const void*>(&gemm8p<0>),
                                        hipFuncAttributeMaxDynamicSharedMemorySize, 131072);
    hipError_t e1 = hipFuncSetAttribute(reinterpret_cast<const void*>(&gemm8p<1>),
                                        hipFuncAttributeMaxDynamicSharedMemorySize, 131072);
    hipError_t e2 = hipFuncSetAttribute(reinterpret_cast<const void*>(&gemm8p<2>),
                                        hipFuncAttributeMaxDynamicSharedMemorySize, 131072);
    g_big = (e0 == hipSuccess && e1 == hipSuccess && e2 == hipSuccess) ? 1 : 0;
  }

  // 1) x -> bf16
  int n8 = S_LEN * BATCH * D_INP / 8;
  cvt_x_kernel<<<(n8 + 255) / 256, 256, 0, stream>>>(x, xb, n8);
  // 2) weights -> bf16 (+ W_in+W_B fold)
  int hd4 = H_DIM * D_INP / 4;
  prep_w_kernel<<<(hd4 + 255) / 256, 256, 0, stream>>>(Wd, Win, WB, Wc, Wcp, Wdu, Wcb, Wcpb);
  // 3) delta/u projections: M=32768, N=4096, K=1024
  if (g_big) {
    dim3 g1(2 * H_DIM / 256, S_LEN * BATCH / 256);  // 16 x 128 = 2048 blocks
    gemm8p<0><<<g1, 512, 131072, stream>>>(xb, Wdu, D_INP, bd, bi, nullptr, dbuf, ubuf, nullptr);
  } else {
    dim3 g1(2 * H_DIM / 128, S_LEN * BATCH / 128);
    gemm_bt<0><<<g1, 256, 0, stream>>>(xb, Wdu, D_INP, bd, bi, nullptr, dbuf, ubuf, nullptr);
  }
  // 4-6) chunked scan over S (b16x8 lanes, NC=64 -> 1024-block grids)
  scan_a_kernel<<<NC * BH8 / 256, 256, 0, stream>>>(dbuf, ubuf, P, Q);
  scan_b_kernel<<<BH / 256, 256, 0, stream>>>(P, Q, Hs);
  scan_c_kernel<<<NC * BH8 / 256, 256, 0, stream>>>(dbuf, ubuf, Hs, hsel);
  // 7) C projection at odd timesteps, fused *h: M=16384, N=2048, K=1024
  if (g_big) {
    dim3 g2(H_DIM / 256, SC * BATCH / 256);  // 8 x 64 = 512 blocks
    gemm8p<1><<<g2, 512, 131072, stream>>>(xb, Wcb, D_INP, nullptr, nullptr, hsel, ysel, nullptr, nullptr);
  } else {
    dim3 g2(H_DIM / 128, SC * BATCH / 128);
    gemm_bt<1><<<g2, 256, 0, stream>>>(xb, Wcb, D_INP, nullptr, nullptr, hsel, ysel, nullptr, nullptr);
  }
  // 8) compress: M=16384, N=1024, K=2048, fp32 out + b_comp
  if (g_big) {
    dim3 g3(D_INP / 256, SC * BATCH / 256);  // 4 x 64 = 256 blocks
    gemm8p<2><<<g3, 512, 131072, stream>>>(ysel, Wcpb, H_DIM, bc, nullptr, nullptr, nullptr, nullptr, out);
  } else {
    dim3 g3(D_INP / 128, SC * BATCH / 128);
    gemm_bt<2><<<g3, 256, 0, stream>>>(ysel, Wcpb, H_DIM, bc, nullptr, nullptr, nullptr, nullptr, out);
  }
}